// Round 1
// baseline (375.761 us; speedup 1.0000x reference)
//
#include <hip/hip_runtime.h>
#include <stdint.h>

#define BB  32
#define CIN 128
#define CO  256
#define HH  64
#define WW  64
#define HW  4096
#define OH  62
#define OW  62
#define OHW 3844

typedef __attribute__((ext_vector_type(8))) short  short8;   // 8 x bf16
typedef __attribute__((ext_vector_type(4))) float  f32x4;
typedef __attribute__((ext_vector_type(4))) ushort ushort4v;

__device__ __forceinline__ ushort f2bf(float f) {
  uint32_t u = __builtin_bit_cast(uint32_t, f);
  u += 0x7FFFu + ((u >> 16) & 1u);
  return (ushort)(u >> 16);
}
__device__ __forceinline__ float bf2f(ushort h) {
  uint32_t u = ((uint32_t)h) << 16;
  return __builtin_bit_cast(float, u);
}

// ---- k0: transpose + bf16-cast weights: w[ci][co] -> wt[co][ci] ----
__global__ void k_wt(const float* __restrict__ w, ushort* __restrict__ wt,
                     int kdim, int ndim) {
  int e = blockIdx.x * 256 + threadIdx.x;
  if (e >= kdim * ndim) return;
  int co = e / kdim, ci = e - co * kdim;
  wt[e] = f2bf(w[(size_t)ci * ndim + co]);
}

// ---- GEMM: out[b][hw][co] = sum_ci src[..ci..] * wt[co][ci] + bias[co]
// A = W (M=co, K=ci) from wt[co][ci] (K-contiguous)
// B = X (K=ci, N=hw) from LDS Xq[hw][ci] (K-contiguous)
// GATHER: src = fp32 x in NCHW, fold transpose+bf16 into staging.
// else:   src = bf16 [b][hw][ci] rows (row stride = ktot).
template<bool GATHER>
__global__ __launch_bounds__(512) void k_gemm(
    const void* __restrict__ src, const ushort* __restrict__ wt,
    const float* __restrict__ bias, ushort* __restrict__ out,
    int hw_total, int ktot)
{
  __shared__ union {
    struct { ushort Wq[256][40]; ushort Xq[64][40]; } s;  // per-kstep tiles (pad 8)
    ushort Rp[64][260];                                   // epilogue repack (pad 4)
  } U;
  __shared__ float biasS[256];

  const int t    = threadIdx.x;
  const int b    = blockIdx.y;
  const int hw0  = blockIdx.x * 64;
  const int wid  = t >> 6;
  const int lane = t & 63;
  const int wn   = wid & 3;     // co quarter (64 co)
  const int wm   = wid >> 2;    // hw half (32 hw)
  const int l15  = lane & 15;
  const int l4   = lane >> 4;

  if (t < 256) biasS[t] = bias[t];

  f32x4 acc[4][2];
  #pragma unroll
  for (int i = 0; i < 4; ++i)
    #pragma unroll
    for (int j = 0; j < 2; ++j)
      #pragma unroll
      for (int k = 0; k < 4; ++k) acc[i][j][k] = 0.f;

  const int ksteps = ktot >> 5;
  for (int ks = 0; ks < ksteps; ++ks) {
    const int ci0 = ks * 32;
    __syncthreads();   // previous mfma reads done (and biasS on first iter)

    // stage W slice: 256 co x 32 ci  (1024 chunks of 8 bf16)
    #pragma unroll
    for (int it = 0; it < 2; ++it) {
      int c  = it * 512 + t;
      int co = c >> 2, seg = c & 3;
      const ushort* p = wt + (size_t)co * ktot + ci0 + seg * 8;
      short8 v = *(const short8*)p;
      *(short8*)&U.s.Wq[co][seg * 8] = v;
    }
    // stage X slice: 64 hw x 32 ci
    if (t < 256) {
      if (GATHER) {
        int hw = t & 63, g = t >> 6;     // g: 0..3, 8 ci each
        const float* xp = (const float*)src
            + (size_t)b * CIN * HW + (size_t)(ci0 + g * 8) * HW + hw0 + hw;
        short8 v;
        #pragma unroll
        for (int i = 0; i < 8; ++i) v[i] = (short)f2bf(xp[(size_t)i * HW]);
        *(short8*)&U.s.Xq[hw][g * 8] = v;
      } else {
        int hw = t >> 2, seg = t & 3;
        short8 v;
        if (hw0 + hw < hw_total) {
          const ushort* p = (const ushort*)src
              + (size_t)b * hw_total * ktot + (size_t)(hw0 + hw) * ktot + ci0 + seg * 8;
          v = *(const short8*)p;
        } else {
          #pragma unroll
          for (int i = 0; i < 8; ++i) v[i] = 0;
        }
        *(short8*)&U.s.Xq[hw][seg * 8] = v;
      }
    }
    __syncthreads();

    short8 af[4], bx[2];
    #pragma unroll
    for (int i = 0; i < 4; ++i)
      af[i] = *(const short8*)&U.s.Wq[wn * 64 + i * 16 + l15][l4 * 8];
    #pragma unroll
    for (int j = 0; j < 2; ++j)
      bx[j] = *(const short8*)&U.s.Xq[wm * 32 + j * 16 + l15][l4 * 8];
    #pragma unroll
    for (int i = 0; i < 4; ++i)
      #pragma unroll
      for (int j = 0; j < 2; ++j)
        acc[i][j] = __builtin_amdgcn_mfma_f32_16x16x32_bf16(af[i], bx[j], acc[i][j], 0, 0, 0);
  }

  __syncthreads();   // all frag reads done before Rp overwrites Wq/Xq

  // epilogue: bias + bf16, repack to [hw][co] in LDS
  #pragma unroll
  for (int i = 0; i < 4; ++i) {
    int co_b = wn * 64 + i * 16 + l4 * 4;           // D row = co
    #pragma unroll
    for (int j = 0; j < 2; ++j) {
      int hw_ = wm * 32 + j * 16 + l15;             // D col = hw
      ushort4v v;
      #pragma unroll
      for (int k = 0; k < 4; ++k)
        v[k] = f2bf(acc[i][j][k] + biasS[co_b + k]);
      *(ushort4v*)&U.Rp[hw_][co_b] = v;
    }
  }
  __syncthreads();

  // coalesced store: rows of 256 bf16 (512B)
  const size_t ob = (size_t)b * hw_total * CO;
  #pragma unroll
  for (int it = 0; it < 8; ++it) {
    int row = it * 8 + (t >> 6);
    int seg = t & 63;
    if (hw0 + row < hw_total) {
      ushort4v v = *(const ushort4v*)&U.Rp[row][seg * 4];
      *(ushort4v*)(out + ob + (size_t)(hw0 + row) * CO + seg * 4) = v;
    }
  }
}

// ---- k2: V1 (along H) + H1 (along W) fused depthwise, VALID. thread = channel.
__global__ __launch_bounds__(256) void k_dw1(
    const ushort* __restrict__ y1t, const float* __restrict__ vw,
    const float* __restrict__ vb, const float* __restrict__ hwt,
    const float* __restrict__ hb, ushort* __restrict__ t1t)
{
  const int c = threadIdx.x, h = blockIdx.x, b = blockIdx.y;
  const float v0 = vw[c * 3 + 0], v1 = vw[c * 3 + 1], v2 = vw[c * 3 + 2];
  const float h0 = hwt[c * 3 + 0], h1 = hwt[c * 3 + 1], h2 = hwt[c * 3 + 2];
  const float cst = vb[c] * (h0 + h1 + h2) + hb[c];
  const ushort* base = y1t + (size_t)b * HW * CO + c;
  ushort* ob = t1t + ((size_t)b * OHW + (size_t)h * OW) * CO + c;

  auto vcol = [&](int s) -> float {
    return v0 * bf2f(base[(size_t)((h + 0) * WW + s) * CO])
         + v1 * bf2f(base[(size_t)((h + 1) * WW + s) * CO])
         + v2 * bf2f(base[(size_t)((h + 2) * WW + s) * CO]);
  };
  float c0 = vcol(0), c1 = vcol(1);
  for (int w = 0; w < OW; ++w) {
    float c2 = vcol(w + 2);
    ob[(size_t)w * CO] = f2bf(h0 * c0 + h1 * c1 + h2 * c2 + cst);
    c0 = c1; c1 = c2;
  }
}

// ---- k4: zero-pad + V2 + H2 fused depthwise; writes fp32 NCHW output.
__global__ __launch_bounds__(256) void k_dw2(
    const ushort* __restrict__ t2t, const float* __restrict__ vw,
    const float* __restrict__ vb, const float* __restrict__ hwt,
    const float* __restrict__ hb, float* __restrict__ outp)
{
  __shared__ float S[256][17];
  const int c = threadIdx.x, h = blockIdx.x, b = blockIdx.y;
  const float v0 = vw[c * 3 + 0], v1 = vw[c * 3 + 1], v2 = vw[c * 3 + 2];
  const float h0 = hwt[c * 3 + 0], h1 = hwt[c * 3 + 1], h2 = hwt[c * 3 + 2];
  const float cst = vb[c] * (h0 + h1 + h2) + hb[c];
  const ushort* base = t2t + (size_t)b * OHW * CO + c;
  const bool rm = (h - 1 >= 0), rp = (h + 1 < OH);

  auto vcol = [&](int s) -> float {   // s is a valid t2 column (0..61)
    float a = v1 * bf2f(base[(size_t)(h * OW + s) * CO]);
    if (rm) a += v0 * bf2f(base[(size_t)((h - 1) * OW + s) * CO]);
    if (rp) a += v2 * bf2f(base[(size_t)((h + 1) * OW + s) * CO]);
    return a;
  };

  float c0 = 0.f;           // Vcol(-1): padded column
  float c1 = vcol(0);
  float* outb = outp + (size_t)b * CO * OHW + (size_t)h * OW;

  for (int chunk = 0; chunk < 4; ++chunk) {
    int w0 = chunk * 16;
    #pragma unroll
    for (int jj = 0; jj < 16; ++jj) {
      int w = w0 + jj;
      if (w < OW) {
        float c2 = (w + 1 < OW) ? vcol(w + 1) : 0.f;  // Vcol(62) is padded
        S[c][jj] = h0 * c0 + h1 * c1 + h2 * c2 + cst;
        c0 = c1; c1 = c2;
      }
    }
    __syncthreads();
    int wloc = c & 15, cg = c >> 4;
    #pragma unroll
    for (int k = 0; k < 16; ++k) {
      int cc = k * 16 + cg;
      if (w0 + wloc < OW)
        outb[(size_t)cc * OHW + w0 + wloc] = S[cc][wloc];
    }
    __syncthreads();
  }
}

extern "C" void kernel_launch(void* const* d_in, const int* in_sizes, int n_in,
                              void* d_out, int out_size, void* d_ws, size_t ws_size,
                              hipStream_t stream) {
  const float* x   = (const float*)d_in[0];
  const float* L1w = (const float*)d_in[1];
  const float* L1b = (const float*)d_in[2];
  const float* V1w = (const float*)d_in[3];
  const float* V1b = (const float*)d_in[4];
  const float* H1w = (const float*)d_in[5];
  const float* H1b = (const float*)d_in[6];
  const float* L2w = (const float*)d_in[7];
  const float* L2b = (const float*)d_in[8];
  const float* V2w = (const float*)d_in[9];
  const float* V2b = (const float*)d_in[10];
  const float* H2w = (const float*)d_in[11];
  const float* H2b = (const float*)d_in[12];

  char* ws = (char*)d_ws;
  ushort* y1t = (ushort*)ws;                                 // 67,108,864 B
  ushort* w1t = (ushort*)(ws + (size_t)67108864);            //     65,536 B
  ushort* w2t = (ushort*)(ws + (size_t)67108864 + 65536);    //    131,072 B
  ushort* t2t = (ushort*)ws;                                 // reuse y1t space
  ushort* t1t = (ushort*)d_out;                              // d_out as scratch (first 63 MB)

  k_wt<<<dim3((CIN * CO + 255) / 256), dim3(256), 0, stream>>>(L1w, w1t, CIN, CO);
  k_wt<<<dim3((CO * CO + 255) / 256), dim3(256), 0, stream>>>(L2w, w2t, CO, CO);

  // L1: x (fp32 NCHW) -> y1t [b][4096][256] bf16
  k_gemm<true><<<dim3(HW / 64, BB), dim3(512), 0, stream>>>(
      (const void*)x, w1t, L1b, y1t, HW, CIN);

  // V1+H1 -> t1t [b][3844][256] bf16 (in d_out)
  k_dw1<<<dim3(OH, BB), dim3(256), 0, stream>>>(y1t, V1w, V1b, H1w, H1b, t1t);

  // L2: t1t -> t2t [b][3844][256] bf16
  k_gemm<false><<<dim3((OHW + 63) / 64, BB), dim3(512), 0, stream>>>(
      (const void*)t1t, w2t, L2b, t2t, OHW, CO);

  // pad + V2 + H2 -> d_out fp32 NCHW
  k_dw2<<<dim3(OH, BB), dim3(256), 0, stream>>>(t2t, V2w, V2b, H2w, H2b, (float*)d_out);
}